// Round 1
// baseline (5852.425 us; speedup 1.0000x reference)
//
#include <hip/hip_runtime.h>

#define HH 1024
#define CC 56
#define TT 64
#define GRID 256
#define NT 256
#define LEAVES 16
#define AGENT __HIP_MEMORY_SCOPE_AGENT

__device__ __forceinline__ float wredsum(float v) {
#pragma unroll
  for (int m = 32; m; m >>= 1) v += __shfl_xor(v, m, 64);
  return v;
}

__device__ __forceinline__ float sigm(float x) { return 1.f / (1.f + __expf(-x)); }
__device__ __forceinline__ float ftanh(float x) {
  x = fminf(15.f, fmaxf(-15.f, x));
  float e = __expf(2.f * x);
  return (e - 1.f) / (e + 1.f);
}

// wave-cooperative dot of one weight row (row-major, 16B aligned) with an LDS vector
__device__ __forceinline__ float wdot(const float* __restrict__ wrow, const float* v, int n4, int lane) {
  const float4* w4 = (const float4*)wrow;
  const float4* v4 = (const float4*)v;
  float acc = 0.f;
  for (int i = lane; i < n4; i += 64) {
    float4 a = w4[i], bb = v4[i];
    acc = fmaf(a.x, bb.x, acc);
    acc = fmaf(a.y, bb.y, acc);
    acc = fmaf(a.z, bb.z, acc);
    acc = fmaf(a.w, bb.w, acc);
  }
  return wredsum(acc);
}

// two-level generation grid barrier; g is the monotonically increasing barrier index (1-based).
// Counters never reset: at barrier g the leaf counter reaches g*(GRID/LEAVES), root reaches g*LEAVES.
__device__ __forceinline__ void gbar(int* iws, int g, int b) {
  __syncthreads();
  if (threadIdx.x == 0) {
    int* leafc = iws + 96 + 32 * (b & (LEAVES - 1));
    int old = __hip_atomic_fetch_add(leafc, 1, __ATOMIC_ACQ_REL, AGENT);
    if (old == g * (GRID / LEAVES) - 1) {
      int rold = __hip_atomic_fetch_add(iws + 64, 1, __ATOMIC_ACQ_REL, AGENT);
      if (rold == g * LEAVES - 1)
        __hip_atomic_store(iws + 32, g, __ATOMIC_RELEASE, AGENT);
    }
    while (__hip_atomic_load(iws + 32, __ATOMIC_RELAXED, AGENT) < g)
      __builtin_amdgcn_s_sleep(1);
    (void)__hip_atomic_load(iws + 32, __ATOMIC_ACQUIRE, AGENT);  // one cache-acquire after spin
  }
  __syncthreads();
}

__global__ void __launch_bounds__(NT, 4) predcells(
    const float* __restrict__ inp,
    const float* __restrict__ W0w, const float* __restrict__ W0b,
    const float* __restrict__ W1w, const float* __restrict__ W1b,
    const float* __restrict__ W2w, const float* __restrict__ W2b,
    const float* __restrict__ Wi1, const float* __restrict__ b1,
    const float* __restrict__ Wi2, const float* __restrict__ b2,
    const float* __restrict__ Wi3, const float* __restrict__ b3,
    const float* __restrict__ V1w, const float* __restrict__ V1b,
    const float* __restrict__ V2w, const float* __restrict__ V2b,
    const float* __restrict__ V3w, const float* __restrict__ V3b,
    const int* __restrict__ itn,
    float* __restrict__ out, int* iws, float* fws)
{
  const int tid = threadIdx.x;
  const int lane = tid & 63;
  const int wv = tid >> 6;
  const int b = blockIdx.x;
  const int i4 = tid * 4;

  // carry + stage vectors in workspace (all offsets 16B-aligned)
  float* TD1 = fws;            // 1024
  float* TD2 = fws + 1024;     // 1024
  float* recon1 = fws + 2048;  // 64 (56 used)
  float* recon2 = fws + 2112;  // 1024
  float* recon3 = fws + 3136;  // 1024
  float* BU0 = fws + 4160;     // 1024
  float* s1  = fws + 5184;     // 1024
  float* BU1 = fws + 6208;     // 1024
  float* s2  = fws + 7232;     // 1024
  float* BU2 = fws + 8256;     // 1024
  float* s3  = fws + 9280;     // 1024

  __shared__ __align__(16) float lv[2048];

  // ---- init behind a release/acquire ready flag (ws is poisoned 0xAA each launch)
  if (b == 0) {
    for (int i = tid; i < 4160; i += NT) fws[i] = 0.f;  // TD1,TD2,recon1..3 = 0
    if (tid < LEAVES) iws[96 + 32 * tid] = 0;
    if (tid == 0) { iws[64] = 0; iws[32] = 0; }
    __syncthreads();
    if (tid == 0) __hip_atomic_store(iws, 0x5D17C0DE, __ATOMIC_RELEASE, AGENT);
  }
  if (tid == 0) {
    while (__hip_atomic_load(iws, __ATOMIC_ACQUIRE, AGENT) != 0x5D17C0DE)
      __builtin_amdgcn_s_sleep(1);
  }
  __syncthreads();

  const float lam = (itn[0] <= 1000) ? 1e-4f : 1e-2f;
  const float lam2 = lam * lam;
  float loss = 0.f;
  int g = 0;
  const int r = b * 4 + wv;  // this wave's row id in [0,1024)

  for (int t = 0; t < TT; ++t) {
    const float* x = inp + t * CC;

    // ---- St1: nTD0 = x - recon1 ; BU0 = W0w @ nTD0 + W0b ; loss += sum|nTD0|
    {
      float acc = 0.f, ls = 0.f;
      if (lane < 14) {  // 56 floats = 14 float4
        const float4 a  = ((const float4*)(W0w + r * CC))[lane];
        const float4 xv = ((const float4*)x)[lane];
        const float4 rv = ((const float4*)recon1)[lane];
        const float dx = xv.x - rv.x, dy = xv.y - rv.y, dz = xv.z - rv.z, dw = xv.w - rv.w;
        acc = a.x * dx + a.y * dy + a.z * dz + a.w * dw;
        ls = fabsf(dx) + fabsf(dy) + fabsf(dz) + fabsf(dw);
      }
      acc = wredsum(acc);
      if (lane == 0) BU0[r] = acc + W0b[r];
      if (b == 0 && wv == 0) loss += wredsum(ls);
    }
    gbar(iws, ++g, b);

    // ---- St2: s1 = lstm(Wi1 @ [BU0;TD1] + b1)   (f-gate rows skipped)
    {
      *(float4*)&lv[i4]        = *(const float4*)&BU0[i4];
      *(float4*)&lv[1024 + i4] = *(const float4*)&TD1[i4];
      __syncthreads();
      float zi = wdot(Wi1 + r * 2048, lv, 512, lane) + b1[r];
      float zg = wdot(Wi1 + (r + 2048) * 2048, lv, 512, lane) + b1[r + 2048];
      float zo = wdot(Wi1 + (r + 3072) * 2048, lv, 512, lane) + b1[r + 3072];
      if (lane == 0) s1[r] = sigm(zo) * ftanh(sigm(zi) * ftanh(zg));
    }
    gbar(iws, ++g, b);

    // ---- St3: nTD1 = s1-recon2 ; BU1 = W1@nTD1+W1b ; nrecon1 = V1@s1+V1b ; TD1<-nTD1 ; loss += lam*sum|nTD1|
    {
      const float4 sv = *(const float4*)&s1[i4];
      const float4 rv = *(const float4*)&recon2[i4];
      float4 d; d.x = sv.x - rv.x; d.y = sv.y - rv.y; d.z = sv.z - rv.z; d.w = sv.w - rv.w;
      *(float4*)&lv[i4] = d;
      *(float4*)&lv[1024 + i4] = sv;
      if (b == 0) *(float4*)&TD1[i4] = d;
      __syncthreads();
      float acc = wdot(W1w + r * 1024, lv, 256, lane);
      if (lane == 0) BU1[r] = acc + W1b[r];
      if (wv == 1 && b < CC) {
        float a2 = wdot(V1w + b * 1024, lv + 1024, 256, lane);
        if (lane == 0) recon1[b] = a2 + V1b[b];
      }
      if (b == 0 && wv == 0) {
        float s = 0.f;
        for (int i = lane; i < 256; i += 64) {
          float4 dd = ((const float4*)lv)[i];
          s += fabsf(dd.x) + fabsf(dd.y) + fabsf(dd.z) + fabsf(dd.w);
        }
        loss += lam * wredsum(s);
      }
    }
    gbar(iws, ++g, b);

    // ---- St4: s2 = lstm(Wi2 @ [BU1;TD2] + b2)
    {
      *(float4*)&lv[i4]        = *(const float4*)&BU1[i4];
      *(float4*)&lv[1024 + i4] = *(const float4*)&TD2[i4];
      __syncthreads();
      float zi = wdot(Wi2 + r * 2048, lv, 512, lane) + b2[r];
      float zg = wdot(Wi2 + (r + 2048) * 2048, lv, 512, lane) + b2[r + 2048];
      float zo = wdot(Wi2 + (r + 3072) * 2048, lv, 512, lane) + b2[r + 3072];
      if (lane == 0) s2[r] = sigm(zo) * ftanh(sigm(zi) * ftanh(zg));
    }
    gbar(iws, ++g, b);

    // ---- St5: nTD2 = s2-recon3 ; BU2 = W2@nTD2+W2b ; nrecon2 = V2@s2+V2b ; TD2<-nTD2 ; loss += lam2*sum|nTD2|
    {
      const float4 sv = *(const float4*)&s2[i4];
      const float4 rv = *(const float4*)&recon3[i4];
      float4 d; d.x = sv.x - rv.x; d.y = sv.y - rv.y; d.z = sv.z - rv.z; d.w = sv.w - rv.w;
      *(float4*)&lv[i4] = d;
      *(float4*)&lv[1024 + i4] = sv;
      if (b == 0) *(float4*)&TD2[i4] = d;
      __syncthreads();
      float aw = wdot(W2w + r * 1024, lv, 256, lane);
      if (lane == 0) BU2[r] = aw + W2b[r];
      float av = wdot(V2w + r * 1024, lv + 1024, 256, lane);
      if (lane == 0) recon2[r] = av + V2b[r];
      if (b == 0 && wv == 0) {
        float s = 0.f;
        for (int i = lane; i < 256; i += 64) {
          float4 dd = ((const float4*)lv)[i];
          s += fabsf(dd.x) + fabsf(dd.y) + fabsf(dd.z) + fabsf(dd.w);
        }
        loss += lam2 * wredsum(s);
      }
    }
    gbar(iws, ++g, b);

    // ---- St6: s3 = lstm(Wi3 @ BU2 + b3)
    {
      *(float4*)&lv[i4] = *(const float4*)&BU2[i4];
      __syncthreads();
      float zi = wdot(Wi3 + r * 1024, lv, 256, lane) + b3[r];
      float zg = wdot(Wi3 + (r + 2048) * 1024, lv, 256, lane) + b3[r + 2048];
      float zo = wdot(Wi3 + (r + 3072) * 1024, lv, 256, lane) + b3[r + 3072];
      if (lane == 0) s3[r] = sigm(zo) * ftanh(sigm(zi) * ftanh(zg));
    }
    gbar(iws, ++g, b);

    // ---- St7: nrecon3 = V3 @ s3 + V3b -> recon3
    {
      *(float4*)&lv[i4] = *(const float4*)&s3[i4];
      __syncthreads();
      float av = wdot(V3w + r * 1024, lv, 256, lane);
      if (lane == 0) recon3[r] = av + V3b[r];
    }
    gbar(iws, ++g, b);
  }

  if (b == 0 && tid == 0) out[0] = loss;
}

extern "C" void kernel_launch(void* const* d_in, const int* in_sizes, int n_in,
                              void* d_out, int out_size, void* d_ws, size_t ws_size,
                              hipStream_t stream) {
  const float* inp = (const float*)d_in[0];
  const float* W0w = (const float*)d_in[1];
  const float* W0b = (const float*)d_in[2];
  const float* W1w = (const float*)d_in[3];
  const float* W1b = (const float*)d_in[4];
  const float* W2w = (const float*)d_in[5];
  const float* W2b = (const float*)d_in[6];
  const float* Wi1 = (const float*)d_in[7];
  const float* b1  = (const float*)d_in[8];
  const float* Wi2 = (const float*)d_in[9];
  const float* b2  = (const float*)d_in[10];
  const float* Wi3 = (const float*)d_in[11];
  const float* b3  = (const float*)d_in[12];
  const float* V1w = (const float*)d_in[13];
  const float* V1b = (const float*)d_in[14];
  const float* V2w = (const float*)d_in[15];
  const float* V2b = (const float*)d_in[16];
  const float* V3w = (const float*)d_in[17];
  const float* V3b = (const float*)d_in[18];
  const int*   itn = (const int*)d_in[19];

  int*   iws = (int*)d_ws;
  float* fws = (float*)((char*)d_ws + 4096);

  hipLaunchKernelGGL(predcells, dim3(GRID), dim3(NT), 0, stream,
                     inp, W0w, W0b, W1w, W1b, W2w, W2b,
                     Wi1, b1, Wi2, b2, Wi3, b3,
                     V1w, V1b, V2w, V2b, V3w, V3b, itn,
                     (float*)d_out, iws, fws);
}